// Round 1
// baseline (3439.212 us; speedup 1.0000x reference)
//
#include <hip/hip_runtime.h>
#include <hip/hip_bf16.h>

// SNN + STDP fused simulation.
// Key structural fact: the recurrence decomposes over output neurons n.
// Each block owns NS neurons and simulates all T steps independently.
// pre_tr (input-only) is precomputed as a bf16 timeline + fp32 column sums S.
// x_t is 5% sparse binary -> bitmask-driven gathers for I and dW terms.

#define TT    350
#define BB    128
#define INF   784
#define NNEU  400
#define NS    4            // neurons per block
#define NTHR  512          // threads per block (b = tid&127, nl = tid>>7)
#define RWORDS 13          // ceil(784/64)
#define RTOT  (BB*RWORDS)  // 1664 u64 per step

#define ALPHA 0.9f
#define BETA  0.8f
#define BPLUS 0.9f
#define BMIN  0.9f
#define CP    (0.008f/128.0f)
#define CM    (0.0008f/128.0f)

__device__ __forceinline__ float bf2f(__hip_bfloat16 v){ return __bfloat162float(v); }

// ---- pre-pass 1: pre_tr timeline (fp32 recurrence, stored bf16) ----
__global__ void k_pretr(const float* __restrict__ img, __hip_bfloat16* __restrict__ pre){
  int idx = blockIdx.x*blockDim.x + threadIdx.x;      // (b,i) flat
  if (idx >= BB*INF) return;
  float v = 0.f;
  for (int t=0;t<TT;t++){
    v = BPLUS*v + img[(size_t)t*(BB*INF) + idx];
    pre[(size_t)t*(BB*INF) + idx] = __float2bfloat16(v);
  }
}

// ---- pre-pass 2: column bitmasks of x (bit b set if x[t,b,i]>0) ----
__global__ void k_colmask(const float* __restrict__ img, ulonglong2* __restrict__ colm){
  int idx = blockIdx.x*blockDim.x + threadIdx.x;      // t*INF + i
  if (idx >= TT*INF) return;
  int t = idx / INF, i = idx - t*INF;
  const float* p = img + (size_t)t*(BB*INF) + i;
  unsigned long long m0=0, m1=0;
  for (int b=0;b<64;b++)  if (p[(size_t)b*INF]      > 0.f) m0 |= 1ull<<b;
  for (int b=0;b<64;b++)  if (p[(size_t)(64+b)*INF] > 0.f) m1 |= 1ull<<b;
  ulonglong2 v; v.x=m0; v.y=m1;
  colm[idx] = v;
}

// ---- pre-pass 3: row bitmasks of x via wave ballot ----
__global__ void k_rowmask(const float* __restrict__ img, unsigned long long* __restrict__ rowm){
  int gid  = blockIdx.x*blockDim.x + threadIdx.x;
  int wid  = gid >> 6;                                // (t*BB + b)
  int lane = gid & 63;
  if (wid >= TT*BB) return;
  const float* p = img + (size_t)wid*INF;
  for (int w=0; w<RWORDS; w++){
    int i = w*64 + lane;
    bool bit = (i < INF) && (p[i] > 0.f);
    unsigned long long m = __ballot(bit);
    if (lane==0) rowm[(size_t)wid*RWORDS + w] = m;
  }
}

// ---- pre-pass 4: S[t,i] = sum_b pre_bf16[t,b,i] (fp32 accum) ----
__global__ void k_S(const __hip_bfloat16* __restrict__ pre, float* __restrict__ S){
  int idx = blockIdx.x*blockDim.x + threadIdx.x;      // t*INF + i
  if (idx >= TT*INF) return;
  int t = idx / INF, i = idx - t*INF;
  const __hip_bfloat16* p = pre + (size_t)t*(BB*INF) + i;
  float s = 0.f;
  for (int b=0;b<BB;b++) s += bf2f(p[(size_t)b*INF]);
  S[idx] = s;
}

// ---- main: per-block independent simulation of NS neurons over T steps ----
__launch_bounds__(NTHR, 1)
__global__ void k_main(const float* __restrict__ Win,
                       const __hip_bfloat16* __restrict__ pre,
                       const float* __restrict__ S,
                       const unsigned long long* __restrict__ rowm,
                       const ulonglong2* __restrict__ colm,
                       float* __restrict__ out){
  __shared__ float Wl[NS][INF];                 // 12.25 KB  block's W rows
  __shared__ unsigned long long rml[RTOT];      // 13.0 KB   row masks (this step)
  __shared__ float postl[BB][NS+1];             // 2.5 KB    post_tr (padded)
  __shared__ unsigned long long spkm[NS][2];    // spike masks over b
  __shared__ float cnt[NS];

  const int tid = threadIdx.x;
  const int n0  = blockIdx.x * NS;
  const int b   = tid & (BB-1);
  const int nl  = tid >> 7;                     // 0..NS-1

  for (int r=0;r<NS;r++)
    for (int i=tid;i<INF;i+=NTHR) Wl[r][i] = Win[(size_t)(n0+r)*INF + i];
  postl[b][nl] = 0.f;
  if (tid < NS) cnt[tid] = 0.f;

  float syn=0.f, mem=0.f, spkcnt=0.f;

  // double-buffered row-mask staging through registers
  unsigned long long rbuf[4];
  #pragma unroll
  for (int j=0;j<4;j++){ int k = tid + j*NTHR; rbuf[j] = (k<RTOT) ? rowm[k] : 0ull; }

  for (int t=0;t<TT;t++){
    #pragma unroll
    for (int j=0;j<4;j++){ int k = tid + j*NTHR; if (k<RTOT) rml[k] = rbuf[j]; }
    __syncthreads();                            // rml ready; prev-step W updates done
    if (t+1 < TT){
      const unsigned long long* rn = rowm + (size_t)(t+1)*RTOT;
      #pragma unroll
      for (int j=0;j<4;j++){ int k = tid + j*NTHR; if (k<RTOT) rbuf[j] = rn[k]; }
    }
    // prefetch this step's colmask + S (consumed in dW phase, hides under I)
    const ulonglong2* cmt = colm + (size_t)t*INF;
    const float*      St  = S    + (size_t)t*INF;
    ulonglong2 cw0 = cmt[tid];
    float      Si0 = St[tid];
    ulonglong2 cw1; cw1.x=0; cw1.y=0;
    float      Si1 = 0.f;
    const int  i1  = NTHR + tid;
    if (i1 < INF){ cw1 = cmt[i1]; Si1 = St[i1]; }

    // ---- I = x_t . W^T  (sparse gather over row bits) ----
    float I = 0.f;
    {
      const unsigned long long* rm = &rml[b*RWORDS];
      const float* wrow = &Wl[nl][0];
      for (int w=0; w<RWORDS; w++){
        unsigned long long m = rm[w];
        int base = w*64;
        while (m){
          int i = base + __builtin_ctzll(m);
          m &= m-1;
          I += wrow[i];
        }
      }
    }
    // ---- elementwise LIF update (reset from pre-update mem) ----
    float reset = (mem > 1.0f) ? 1.0f : 0.0f;
    syn = ALPHA*syn + I;
    mem = BETA*mem + syn - reset;
    float spk = (mem > 1.0f) ? 1.0f : 0.0f;
    spkcnt += spk;
    float post = BMIN*postl[b][nl] + spk;
    postl[b][nl] = post;
    unsigned long long bal = __ballot(spk > 0.5f);
    if ((tid & 63) == 0) spkm[nl][(tid>>6)&1] = bal;
    __syncthreads();                            // spk masks + post_tr visible

    // ---- dW + W update, threads partition columns i ----
    unsigned long long sm0[NS], sm1[NS]; int pc[NS];
    #pragma unroll
    for (int r=0;r<NS;r++){
      sm0[r]=spkm[r][0]; sm1[r]=spkm[r][1];
      pc[r] = __popcll(sm0[r]) + __popcll(sm1[r]);
    }
    const __hip_bfloat16* pr = pre + (size_t)t*(BB*INF);

    #pragma unroll
    for (int slot=0; slot<2; slot++){
      const int i = (slot==0) ? tid : i1;
      if (i >= INF) break;
      const ulonglong2 cw = (slot==0) ? cw0 : cw1;
      const float      Si = (slot==0) ? Si0 : Si1;
      // depression: sum post_tr over b where x[b,i]=1  (~6.4 bits)
      float dep[NS] = {0.f,0.f,0.f,0.f};
      unsigned long long c = cw.x;
      while (c){ int bb=__builtin_ctzll(c); c&=c-1; const float* pp=postl[bb];
        #pragma unroll
        for (int r=0;r<NS;r++) dep[r]+=pp[r]; }
      c = cw.y;
      while (c){ int bb=64+__builtin_ctzll(c); c&=c-1; const float* pp=postl[bb];
        #pragma unroll
        for (int r=0;r<NS;r++) dep[r]+=pp[r]; }
      // potentiation: direct or complement (S - sum over non-spikers)
      #pragma unroll
      for (int r=0;r<NS;r++){
        unsigned long long m0=sm0[r], m1=sm1[r];
        bool direct = (pc[r] <= BB/2);
        if (!direct){ m0=~m0; m1=~m1; }
        float acc=0.f;
        while (m0){ int bb=__builtin_ctzll(m0); m0&=m0-1; acc += bf2f(pr[(size_t)bb*INF + i]); }
        while (m1){ int bb=64+__builtin_ctzll(m1); m1&=m1-1; acc += bf2f(pr[(size_t)bb*INF + i]); }
        float pot = direct ? acc : (Si - acc);
        float w = Wl[r][i] + CP*pot - CM*dep[r];
        Wl[r][i] = fminf(fmaxf(w, 0.f), 1.f);
      }
    }
    // no barrier here: next iter's rml write / prefetches touch no dW-read data;
    // the loop-top __syncthreads orders W updates before the next I phase.
  }
  __syncthreads();
  // ---- outputs: [W (400x784)] [mem (128x400)] [syn (128x400)] [counts (400)] ----
  for (int r=0;r<NS;r++)
    for (int i=tid;i<INF;i+=NTHR) out[(size_t)(n0+r)*INF + i] = Wl[r][i];
  out[(size_t)NNEU*INF + (size_t)b*NNEU + n0 + nl] = mem;
  out[(size_t)NNEU*INF + (size_t)BB*NNEU + (size_t)b*NNEU + n0 + nl] = syn;
  atomicAdd(&cnt[nl], spkcnt);   // integer-valued fp adds: exact, order-free
  __syncthreads();
  if (tid < NS) out[(size_t)NNEU*INF + 2*(size_t)BB*NNEU + n0 + tid] = cnt[tid];
}

extern "C" void kernel_launch(void* const* d_in, const int* in_sizes, int n_in,
                              void* d_out, int out_size, void* d_ws, size_t ws_size,
                              hipStream_t stream) {
  const float* img = (const float*)d_in[0];   // [T,B,IN] float32 (0/1)
  const float* W   = (const float*)d_in[1];   // [N,IN] float32
  float* out = (float*)d_out;

  // workspace carve (total ~80.4 MB)
  char* ws = (char*)d_ws;
  __hip_bfloat16*     pre  = (__hip_bfloat16*)ws;                      // 70,246,400
  float*              S    = (float*)(ws + 70246400);                  //  1,097,600
  unsigned long long* rowm = (unsigned long long*)(ws + 71344000);     //  4,659,200
  ulonglong2*         colm = (ulonglong2*)(ws + 76003200);             //  4,390,400

  k_pretr  <<<(BB*INF + 255)/256, 256, 0, stream>>>(img, pre);
  k_colmask<<<(TT*INF + 255)/256, 256, 0, stream>>>(img, colm);
  k_rowmask<<<(TT*BB*64)/256,     256, 0, stream>>>(img, rowm);
  k_S      <<<(TT*INF + 255)/256, 256, 0, stream>>>(pre, S);
  k_main   <<<NNEU/NS, NTHR, 0, stream>>>(W, pre, S, rowm, colm, out);
}

// Round 2
// 836.025 us; speedup vs baseline: 4.1138x; 4.1138x over previous
//
#include <hip/hip_runtime.h>
#include <hip/hip_bf16.h>

// SNN + STDP fused simulation, round 2.
// Structure: recurrence decomposes over neurons; 200 blocks x 2 neurons run all
// 350 steps independently. Divergent bitmask gathers replaced by precomputed
// compact index lists (fixed-count unrolled loops, zero-padded entries).
// I-phase 4-way split combined via shfl_xor (2 barriers/step total).

#define TT    350
#define BB    128
#define INF   784
#define NNEU  400
#define NS    2
#define NTHR  512
#define LCAP  80           // row-list capacity (u16 entries, pad = 784)

#define ALPHA 0.9f
#define BETA  0.8f
#define BPLUS 0.9f
#define BMIN  0.9f
#define CP    (0.008f/128.0f)
#define CM    (0.0008f/128.0f)

__device__ __forceinline__ float bf2f(__hip_bfloat16 v){ return __bfloat162float(v); }

// ---- pre-pass 1: pre_tr timeline (fp32 recurrence, stored bf16) ----
__global__ void k_pretr(const float* __restrict__ img, __hip_bfloat16* __restrict__ pre){
  int idx = blockIdx.x*blockDim.x + threadIdx.x;      // (b,i) flat
  if (idx >= BB*INF) return;
  float v = 0.f;
  for (int t=0;t<TT;t++){
    v = BPLUS*v + img[(size_t)t*(BB*INF) + idx];
    pre[(size_t)t*(BB*INF) + idx] = __float2bfloat16(v);
  }
}

// ---- pre-pass 2: S[t,i] = sum_b pre_bf16[t,b,i] (fp32 accum) ----
__global__ void k_S(const __hip_bfloat16* __restrict__ pre, float* __restrict__ S){
  int idx = blockIdx.x*blockDim.x + threadIdx.x;      // t*INF + i
  if (idx >= TT*INF) return;
  int t = idx / INF, i = idx - t*INF;
  const __hip_bfloat16* p = pre + (size_t)t*(BB*INF) + i;
  float s = 0.f;
  for (int b=0;b<BB;b++) s += bf2f(p[(size_t)b*INF]);
  S[idx] = s;
}

// ---- pre-pass 3: compact row index lists (one wave per (t,b)) ----
__global__ void k_rowlist(const float* __restrict__ img, unsigned short* __restrict__ lists,
                          int* __restrict__ cnts){
  int gid = blockIdx.x*blockDim.x + threadIdx.x;
  int gw = gid >> 6, lane = gid & 63;
  if (gw >= TT*BB) return;
  __shared__ unsigned short buf[4][LCAP];
  int wl = (threadIdx.x >> 6) & 3;
  const float* p = img + (size_t)gw*INF;
  int cnt = 0;
  for (int wdi=0; wdi<13; wdi++){
    int i = wdi*64 + lane;
    bool a = (i < INF) && (p[i] > 0.f);
    unsigned long long bal = __ballot(a);
    int pos = cnt + __popcll(bal & ((1ull<<lane)-1ull));
    if (a && pos < LCAP) buf[wl][pos] = (unsigned short)i;
    cnt += __popcll(bal);
  }
  for (int k = cnt + lane; k < LCAP; k += 64) buf[wl][k] = (unsigned short)INF;
  if (lane == 0) cnts[gw] = (cnt < LCAP) ? cnt : LCAP;
  if (lane < LCAP/2)
    ((unsigned int*)(lists + (size_t)gw*LCAP))[lane] = ((unsigned int*)buf[wl])[lane];
}

// ---- pre-pass 4: column byte-lists: 32B per (t,i): [cnt, entries..., pad=128] ----
__global__ void k_collist(const float* __restrict__ img, unsigned int* __restrict__ collist){
  int idx = blockIdx.x*blockDim.x + threadIdx.x;      // t*INF + i
  if (idx >= TT*INF) return;
  int t = idx / INF, i = idx - t*INF;
  const float* p = img + (size_t)t*(BB*INF) + i;
  unsigned long long m0=0, m1=0;
  for (int b=0;b<64;b++) m0 |= ((unsigned long long)(p[(size_t)b*INF]      > 0.f)) << b;
  for (int b=0;b<64;b++) m1 |= ((unsigned long long)(p[(size_t)(64+b)*INF] > 0.f)) << b;
  int cnt = __popcll(m0) + __popcll(m1);
  unsigned int w[8];
  w[0] = (unsigned int)cnt; w[1]=0;w[2]=0;w[3]=0;w[4]=0;w[5]=0;w[6]=0;w[7]=0;
  #pragma unroll
  for (int k=1;k<32;k++){
    int bb;
    if (m0){ bb = __builtin_ctzll(m0); m0 &= m0-1; }
    else if (m1){ bb = 64 + __builtin_ctzll(m1); m1 &= m1-1; }
    else bb = 128;
    w[k>>2] |= ((unsigned int)bb) << ((k&3)*8);
  }
  uint4* dst = (uint4*)(collist + (size_t)idx*8);
  uint4 lo; lo.x=w[0]; lo.y=w[1]; lo.z=w[2]; lo.w=w[3];
  uint4 hi; hi.x=w[4]; hi.y=w[5]; hi.z=w[6]; hi.w=w[7];
  dst[0]=lo; dst[1]=hi;
}

__device__ __forceinline__ float potf(unsigned long long ma, unsigned long long mb,
                                      int pc, float Sv,
                                      const __hip_bfloat16* __restrict__ prt, int c){
  bool direct = (pc <= 64);
  unsigned long long m = direct ? ma : ~ma;
  unsigned long long n = direct ? mb : ~mb;
  float acc = 0.f;
  while (m){ int bb = __builtin_ctzll(m); m &= m-1; acc += bf2f(prt[(size_t)bb*INF + c]); }
  while (n){ int bb = __builtin_ctzll(n); n &= n-1; acc += bf2f(prt[(size_t)(64+bb)*INF + c]); }
  return direct ? acc : (Sv - acc);
}

#define G2(W) { float2 a_ = Wp2[(W) & 0xffffu]; I0 += a_.x; I1 += a_.y; \
                float2 b_ = Wp2[(W) >> 16];     I0 += b_.x; I1 += b_.y; }
#define GATHER8(V) { G2((V).x); G2((V).y); G2((V).z); G2((V).w); }

#define DEP4(W) { float2 p_; \
  p_ = postl[(W) & 0xffu];        d0 += p_.x; d1 += p_.y; \
  p_ = postl[((W)>>8) & 0xffu];   d0 += p_.x; d1 += p_.y; \
  p_ = postl[((W)>>16) & 0xffu];  d0 += p_.x; d1 += p_.y; \
  p_ = postl[(W)>>24];            d0 += p_.x; d1 += p_.y; }

#define DOCOL(c, cl, sv) { \
  float d0=0.f, d1=0.f; \
  unsigned int w0_ = (cl).x; \
  { float2 p_; \
    p_ = postl[(w0_>>8) & 0xffu];  d0 += p_.x; d1 += p_.y; \
    p_ = postl[(w0_>>16) & 0xffu]; d0 += p_.x; d1 += p_.y; \
    p_ = postl[w0_>>24];           d0 += p_.x; d1 += p_.y; } \
  DEP4((cl).y); DEP4((cl).z); DEP4((cl).w); \
  int cc_ = (int)(w0_ & 0xffu); \
  if (cc_ > 15){ \
    uint4 e2_ = *(const uint4*)(collist + ((size_t)t*INF + (c))*8 + 4); \
    DEP4(e2_.x); DEP4(e2_.y); DEP4(e2_.z); DEP4(e2_.w); \
  } \
  float pot0_ = potf(s00, s01, pc0, (sv), prt, (c)); \
  float pot1_ = potf(s10, s11, pc1, (sv), prt, (c)); \
  float2 wv_ = Wp2[(c)]; \
  wv_.x = fminf(fmaxf(wv_.x + CP*pot0_ - CM*d0, 0.f), 1.f); \
  wv_.y = fminf(fmaxf(wv_.y + CP*pot1_ - CM*d1, 0.f), 1.f); \
  Wp2[(c)] = wv_; }

__launch_bounds__(NTHR, 1)
__global__ void k_main(const float* __restrict__ Win,
                       const __hip_bfloat16* __restrict__ pre,
                       const float* __restrict__ S,
                       const unsigned short* __restrict__ lists,
                       const int* __restrict__ cnts,
                       const unsigned int* __restrict__ collist,
                       float* __restrict__ out){
  __shared__ float2 Wp2[800];                  // [i] -> (W[n0][i], W[n0+1][i]); 784.. = 0 pad
  __shared__ float2 postl[132];                // [b] -> (post0, post1); 128.. = 0 pad
  __shared__ unsigned long long smQ[2][2];     // spike masks per neuron
  __shared__ float cntS[2];

  const int tid  = threadIdx.x;
  const int lane = tid & 63;
  const int wv   = tid >> 6;                   // wave 0..7
  const int q    = lane >> 4;                  // 4-way I split
  const int b    = (wv << 4) | (lane & 15);    // batch 0..127
  const int n0   = blockIdx.x * NS;

  for (int i = tid; i < 800; i += NTHR){
    float2 w;
    w.x = (i < INF) ? Win[(size_t)n0*INF + i] : 0.f;
    w.y = (i < INF) ? Win[(size_t)(n0+1)*INF + i] : 0.f;
    Wp2[i] = w;
  }
  if (tid < 132){ postl[tid].x = 0.f; postl[tid].y = 0.f; }
  if (tid < 2) cntS[tid] = 0.f;

  const int c0 = tid;
  const int c1 = tid + NTHR;
  const bool has1 = (c1 < INF);

  float syn0=0.f, mem0=0.f, syn1=0.f, mem1=0.f, sc0=0.f, sc1=0.f;

  // t=0 prefetch
  const unsigned short* lp0 = lists + ((size_t)b)*LCAP + (size_t)q*8;
  uint4 lA = *(const uint4*)lp0;
  uint4 lB = *(const uint4*)(lp0 + 32);
  int cn = cnts[b];
  uint4 cl0 = *(const uint4*)(collist + (size_t)c0*8);
  float sv0 = S[c0];
  uint4 cl1 = cl0; float sv1 = 0.f;
  if (has1){ cl1 = *(const uint4*)(collist + (size_t)c1*8); sv1 = S[c1]; }

  for (int t=0; t<TT; t++){
    __syncthreads();                            // Wp2 updates from prev step visible
    // ---- I partial gather: 16 list entries, both neurons per ds_read_b64 ----
    float I0 = 0.f, I1 = 0.f;
    GATHER8(lA); GATHER8(lB);
    if (cn > 64 + q*8){                         // rare third round (cnt>64)
      uint4 lC = *(const uint4*)(lists + ((size_t)t*BB + b)*LCAP + 64 + (size_t)q*8);
      GATHER8(lC);
    }
    // ---- prefetch t+1 (lands during LIF/dW) ----
    int tn = (t+1 < TT) ? t+1 : TT-1;
    const unsigned short* lpn = lists + ((size_t)tn*BB + b)*LCAP + (size_t)q*8;
    uint4 lAn = *(const uint4*)lpn;
    uint4 lBn = *(const uint4*)(lpn + 32);
    int cnn = cnts[tn*BB + b];
    uint4 cl0n = *(const uint4*)(collist + ((size_t)tn*INF + c0)*8);
    float sv0n = S[tn*INF + c0];
    uint4 cl1n = cl0n; float sv1n = 0.f;
    if (has1){ cl1n = *(const uint4*)(collist + ((size_t)tn*INF + c1)*8); sv1n = S[tn*INF + c1]; }

    // ---- combine 4 partials in-wave ----
    I0 += __shfl_xor(I0, 16); I0 += __shfl_xor(I0, 32);
    I1 += __shfl_xor(I1, 16); I1 += __shfl_xor(I1, 32);

    // ---- LIF (redundant across q, identical fp ops) ----
    float r0 = (mem0 > 1.f) ? 1.f : 0.f;
    syn0 = ALPHA*syn0 + I0;
    mem0 = BETA*mem0 + syn0 - r0;
    float s0 = (mem0 > 1.f) ? 1.f : 0.f;
    float r1 = (mem1 > 1.f) ? 1.f : 0.f;
    syn1 = ALPHA*syn1 + I1;
    mem1 = BETA*mem1 + syn1 - r1;
    float s1 = (mem1 > 1.f) ? 1.f : 0.f;
    unsigned long long bal0 = __ballot(s0 > 0.5f);
    unsigned long long bal1 = __ballot(s1 > 0.5f);
    if (q == 0){
      sc0 += s0; sc1 += s1;
      float2 pv = postl[b];
      pv.x = BMIN*pv.x + s0;
      pv.y = BMIN*pv.y + s1;
      postl[b] = pv;
    }
    if (lane == 0){                             // 16-bit chunk per wave -> 128-bit masks
      ((unsigned short*)smQ)[wv]     = (unsigned short)(bal0 & 0xffffu);
      ((unsigned short*)smQ)[8 + wv] = (unsigned short)(bal1 & 0xffffu);
    }
    __syncthreads();                            // postl + smQ visible

    // ---- dW + W update; threads own columns c0 (and c1) ----
    unsigned long long s00 = smQ[0][0], s01 = smQ[0][1];
    unsigned long long s10 = smQ[1][0], s11 = smQ[1][1];
    int pc0 = __popcll(s00) + __popcll(s01);
    int pc1 = __popcll(s10) + __popcll(s11);
    const __hip_bfloat16* prt = pre + (size_t)t*(BB*INF);
    DOCOL(c0, cl0, sv0)
    if (has1) DOCOL(c1, cl1, sv1)

    lA=lAn; lB=lBn; cn=cnn; cl0=cl0n; sv0=sv0n; cl1=cl1n; sv1=sv1n;
  }

  __syncthreads();
  // ---- outputs: [W (400x784)] [mem (128x400)] [syn (128x400)] [counts (400)] ----
  for (int i = tid; i < INF; i += NTHR){
    float2 wvv = Wp2[i];
    out[(size_t)n0*INF + i]       = wvv.x;
    out[(size_t)(n0+1)*INF + i]   = wvv.y;
  }
  if (q == 0){
    out[(size_t)NNEU*INF + (size_t)b*NNEU + n0]                        = mem0;
    out[(size_t)NNEU*INF + (size_t)b*NNEU + n0 + 1]                    = mem1;
    out[(size_t)NNEU*INF + (size_t)BB*NNEU + (size_t)b*NNEU + n0]      = syn0;
    out[(size_t)NNEU*INF + (size_t)BB*NNEU + (size_t)b*NNEU + n0 + 1]  = syn1;
    atomicAdd(&cntS[0], sc0);
    atomicAdd(&cntS[1], sc1);
  }
  __syncthreads();
  if (tid < 2) out[(size_t)NNEU*INF + 2*(size_t)BB*NNEU + n0 + tid] = cntS[tid];
}

extern "C" void kernel_launch(void* const* d_in, const int* in_sizes, int n_in,
                              void* d_out, int out_size, void* d_ws, size_t ws_size,
                              hipStream_t stream) {
  const float* img = (const float*)d_in[0];   // [T,B,IN] float32 (0/1)
  const float* W   = (const float*)d_in[1];   // [N,IN] float32
  float* out = (float*)d_out;

  // workspace carve (total 87,472,000 B)
  char* ws = (char*)d_ws;
  __hip_bfloat16* pre  = (__hip_bfloat16*)ws;                  // 70,246,400
  float*          S    = (float*)(ws + 70246400);              //  1,097,600
  unsigned short* lst  = (unsigned short*)(ws + 71344000);     //  7,168,000
  int*            cnts = (int*)(ws + 78512000);                //    179,200
  unsigned int*   coll = (unsigned int*)(ws + 78691200);       //  8,780,800

  k_pretr  <<<(BB*INF + 255)/256, 256, 0, stream>>>(img, pre);
  k_S      <<<(TT*INF + 255)/256, 256, 0, stream>>>(pre, S);
  k_rowlist<<<(TT*BB*64)/256,     256, 0, stream>>>(img, lst, cnts);
  k_collist<<<(TT*INF + 255)/256, 256, 0, stream>>>(img, coll);
  k_main   <<<NNEU/NS, NTHR, 0, stream>>>(W, pre, S, lst, cnts, coll, out);
}

// Round 3
// 718.750 us; speedup vs baseline: 4.7850x; 1.1632x over previous
//
#include <hip/hip_runtime.h>
#include <hip/hip_bf16.h>

// SNN + STDP fused simulation, round 3.
// Same decomposition as R2 (200 blocks x 2 neurons, all T steps in-block,
// compact index lists). Change: 1024 threads / 16 waves per block to hide the
// barrier + LDS-latency stalls that dominated R2 (VALUBusy 20%, occ 19%).
// I-split is 8-way (8 entries/thread), dW phase is exactly 1 column/thread.

#define TT    350
#define BB    128
#define INF   784
#define NNEU  400
#define NS    2
#define NTHR  1024
#define LCAP  80           // row-list capacity (u16 entries, pad = 784)

#define ALPHA 0.9f
#define BETA  0.8f
#define BPLUS 0.9f
#define BMIN  0.9f
#define CP    (0.008f/128.0f)
#define CM    (0.0008f/128.0f)

__device__ __forceinline__ float bf2f(__hip_bfloat16 v){ return __bfloat162float(v); }

// ---- pre-pass 1: pre_tr timeline (fp32 recurrence, stored bf16) ----
__global__ void k_pretr(const float* __restrict__ img, __hip_bfloat16* __restrict__ pre){
  int idx = blockIdx.x*blockDim.x + threadIdx.x;      // (b,i) flat
  if (idx >= BB*INF) return;
  float v = 0.f;
  for (int t=0;t<TT;t++){
    v = BPLUS*v + img[(size_t)t*(BB*INF) + idx];
    pre[(size_t)t*(BB*INF) + idx] = __float2bfloat16(v);
  }
}

// ---- pre-pass 2: S[t,i] = sum_b pre_bf16[t,b,i] (fp32 accum) ----
__global__ void k_S(const __hip_bfloat16* __restrict__ pre, float* __restrict__ S){
  int idx = blockIdx.x*blockDim.x + threadIdx.x;      // t*INF + i
  if (idx >= TT*INF) return;
  int t = idx / INF, i = idx - t*INF;
  const __hip_bfloat16* p = pre + (size_t)t*(BB*INF) + i;
  float s = 0.f;
  for (int b=0;b<BB;b++) s += bf2f(p[(size_t)b*INF]);
  S[idx] = s;
}

// ---- pre-pass 3: compact row index lists (one wave per (t,b)) ----
__global__ void k_rowlist(const float* __restrict__ img, unsigned short* __restrict__ lists,
                          int* __restrict__ cnts){
  int gid = blockIdx.x*blockDim.x + threadIdx.x;
  int gw = gid >> 6, lane = gid & 63;
  if (gw >= TT*BB) return;
  __shared__ unsigned short buf[4][LCAP];
  int wl = (threadIdx.x >> 6) & 3;
  const float* p = img + (size_t)gw*INF;
  int cnt = 0;
  for (int wdi=0; wdi<13; wdi++){
    int i = wdi*64 + lane;
    bool a = (i < INF) && (p[i] > 0.f);
    unsigned long long bal = __ballot(a);
    int pos = cnt + __popcll(bal & ((1ull<<lane)-1ull));
    if (a && pos < LCAP) buf[wl][pos] = (unsigned short)i;
    cnt += __popcll(bal);
  }
  for (int k = cnt + lane; k < LCAP; k += 64) buf[wl][k] = (unsigned short)INF;
  if (lane == 0) cnts[gw] = (cnt < LCAP) ? cnt : LCAP;
  if (lane < LCAP/2)
    ((unsigned int*)(lists + (size_t)gw*LCAP))[lane] = ((unsigned int*)buf[wl])[lane];
}

// ---- pre-pass 4: column byte-lists: 32B per (t,i): [cnt, entries..., pad=128] ----
__global__ void k_collist(const float* __restrict__ img, unsigned int* __restrict__ collist){
  int idx = blockIdx.x*blockDim.x + threadIdx.x;      // t*INF + i
  if (idx >= TT*INF) return;
  int t = idx / INF, i = idx - t*INF;
  const float* p = img + (size_t)t*(BB*INF) + i;
  unsigned long long m0=0, m1=0;
  for (int b=0;b<64;b++) m0 |= ((unsigned long long)(p[(size_t)b*INF]      > 0.f)) << b;
  for (int b=0;b<64;b++) m1 |= ((unsigned long long)(p[(size_t)(64+b)*INF] > 0.f)) << b;
  int cnt = __popcll(m0) + __popcll(m1);
  unsigned int w[8];
  w[0] = (unsigned int)cnt; w[1]=0;w[2]=0;w[3]=0;w[4]=0;w[5]=0;w[6]=0;w[7]=0;
  #pragma unroll
  for (int k=1;k<32;k++){
    int bb;
    if (m0){ bb = __builtin_ctzll(m0); m0 &= m0-1; }
    else if (m1){ bb = 64 + __builtin_ctzll(m1); m1 &= m1-1; }
    else bb = 128;
    w[k>>2] |= ((unsigned int)bb) << ((k&3)*8);
  }
  uint4* dst = (uint4*)(collist + (size_t)idx*8);
  uint4 lo; lo.x=w[0]; lo.y=w[1]; lo.z=w[2]; lo.w=w[3];
  uint4 hi; hi.x=w[4]; hi.y=w[5]; hi.z=w[6]; hi.w=w[7];
  dst[0]=lo; dst[1]=hi;
}

__device__ __forceinline__ float potf(unsigned long long ma, unsigned long long mb,
                                      int pc, float Sv,
                                      const __hip_bfloat16* __restrict__ prt, int c){
  bool direct = (pc <= 64);
  unsigned long long m = direct ? ma : ~ma;
  unsigned long long n = direct ? mb : ~mb;
  float acc = 0.f;
  while (m){ int bb = __builtin_ctzll(m); m &= m-1; acc += bf2f(prt[(size_t)bb*INF + c]); }
  while (n){ int bb = __builtin_ctzll(n); n &= n-1; acc += bf2f(prt[(size_t)(64+bb)*INF + c]); }
  return direct ? acc : (Sv - acc);
}

#define G2(W) { float2 a_ = Wp2[(W) & 0xffffu]; I0 += a_.x; I1 += a_.y; \
                float2 b_ = Wp2[(W) >> 16];     I0 += b_.x; I1 += b_.y; }
#define GATHER8(V) { G2((V).x); G2((V).y); G2((V).z); G2((V).w); }

#define DEP4(W) { float2 p_; \
  p_ = postl[(W) & 0xffu];        d0 += p_.x; d1 += p_.y; \
  p_ = postl[((W)>>8) & 0xffu];   d0 += p_.x; d1 += p_.y; \
  p_ = postl[((W)>>16) & 0xffu];  d0 += p_.x; d1 += p_.y; \
  p_ = postl[(W)>>24];            d0 += p_.x; d1 += p_.y; }

#define DOCOL(c, cl, sv) { \
  float d0=0.f, d1=0.f; \
  unsigned int w0_ = (cl).x; \
  { float2 p_; \
    p_ = postl[(w0_>>8) & 0xffu];  d0 += p_.x; d1 += p_.y; \
    p_ = postl[(w0_>>16) & 0xffu]; d0 += p_.x; d1 += p_.y; \
    p_ = postl[w0_>>24];           d0 += p_.x; d1 += p_.y; } \
  DEP4((cl).y); DEP4((cl).z); DEP4((cl).w); \
  int cc_ = (int)(w0_ & 0xffu); \
  if (cc_ > 15){ \
    uint4 e2_ = *(const uint4*)(collist + ((size_t)t*INF + (c))*8 + 4); \
    DEP4(e2_.x); DEP4(e2_.y); DEP4(e2_.z); DEP4(e2_.w); \
  } \
  float pot0_ = potf(s00, s01, pc0, (sv), prt, (c)); \
  float pot1_ = potf(s10, s11, pc1, (sv), prt, (c)); \
  float2 wv_ = Wp2[(c)]; \
  wv_.x = fminf(fmaxf(wv_.x + CP*pot0_ - CM*d0, 0.f), 1.f); \
  wv_.y = fminf(fmaxf(wv_.y + CP*pot1_ - CM*d1, 0.f), 1.f); \
  Wp2[(c)] = wv_; }

__launch_bounds__(NTHR, 1)
__global__ void k_main(const float* __restrict__ Win,
                       const __hip_bfloat16* __restrict__ pre,
                       const float* __restrict__ S,
                       const unsigned short* __restrict__ lists,
                       const int* __restrict__ cnts,
                       const unsigned int* __restrict__ collist,
                       float* __restrict__ out){
  __shared__ float2 Wp2[800];                  // [i] -> (W[n0][i], W[n0+1][i]); 784.. = 0 pad
  __shared__ float2 postl[132];                // [b] -> (post0, post1); 128.. = 0 pad
  __shared__ unsigned long long smQ[2][2];     // spike masks per neuron
  __shared__ float cntS[2];

  const int tid  = threadIdx.x;
  const int lane = tid & 63;
  const int wv   = tid >> 6;                   // wave 0..15
  const int q    = lane >> 3;                  // 8-way I split
  const int b    = (wv << 3) | (lane & 7);     // batch 0..127
  const int n0   = blockIdx.x * NS;

  if (tid < 800){
    float2 w;
    w.x = (tid < INF) ? Win[(size_t)n0*INF + tid] : 0.f;
    w.y = (tid < INF) ? Win[(size_t)(n0+1)*INF + tid] : 0.f;
    Wp2[tid] = w;
  }
  if (tid < 132){ postl[tid].x = 0.f; postl[tid].y = 0.f; }
  if (tid < 2) cntS[tid] = 0.f;

  const int  c0   = tid;
  const bool hasc = (c0 < INF);

  float syn0=0.f, mem0=0.f, syn1=0.f, mem1=0.f, sc0=0.f, sc1=0.f;

  // t=0 prefetch
  const unsigned short* lp0 = lists + ((size_t)b)*LCAP + (size_t)q*8;
  uint4 lA = *(const uint4*)lp0;
  int cn = cnts[b];
  uint4 cl0; cl0.x=0;cl0.y=0;cl0.z=0;cl0.w=0;
  float sv0 = 0.f;
  if (hasc){ cl0 = *(const uint4*)(collist + (size_t)c0*8); sv0 = S[c0]; }

  for (int t=0; t<TT; t++){
    __syncthreads();                            // Wp2 updates from prev step visible
    // ---- I partial gather: 8 list entries, both neurons per ds_read_b64 ----
    float I0 = 0.f, I1 = 0.f;
    GATHER8(lA);
    if (cn > 64 + q*8){                         // entries 64..79 (q=0,1), ~1 occurrence total
      uint4 lC = *(const uint4*)(lists + ((size_t)t*BB + b)*LCAP + 64 + (size_t)q*8);
      GATHER8(lC);
    }
    // ---- prefetch t+1 (lands during LIF/dW) ----
    int tn = (t+1 < TT) ? t+1 : TT-1;
    uint4 lAn = *(const uint4*)(lists + ((size_t)tn*BB + b)*LCAP + (size_t)q*8);
    int cnn = cnts[tn*BB + b];
    uint4 cl0n = cl0; float sv0n = sv0;
    if (hasc){
      cl0n = *(const uint4*)(collist + ((size_t)tn*INF + c0)*8);
      sv0n = S[tn*INF + c0];
    }

    // ---- combine 8 partials in-wave ----
    I0 += __shfl_xor(I0, 8); I0 += __shfl_xor(I0, 16); I0 += __shfl_xor(I0, 32);
    I1 += __shfl_xor(I1, 8); I1 += __shfl_xor(I1, 16); I1 += __shfl_xor(I1, 32);

    // ---- LIF (redundant across q, identical fp ops) ----
    float r0 = (mem0 > 1.f) ? 1.f : 0.f;
    syn0 = ALPHA*syn0 + I0;
    mem0 = BETA*mem0 + syn0 - r0;
    float s0 = (mem0 > 1.f) ? 1.f : 0.f;
    float r1 = (mem1 > 1.f) ? 1.f : 0.f;
    syn1 = ALPHA*syn1 + I1;
    mem1 = BETA*mem1 + syn1 - r1;
    float s1 = (mem1 > 1.f) ? 1.f : 0.f;
    unsigned long long bal0 = __ballot(s0 > 0.5f);
    unsigned long long bal1 = __ballot(s1 > 0.5f);
    if (q == 0){
      sc0 += s0; sc1 += s1;
      float2 pv = postl[b];
      pv.x = BMIN*pv.x + s0;
      pv.y = BMIN*pv.y + s1;
      postl[b] = pv;
    }
    if (lane == 0){                             // 8-bit chunk per wave -> 128-bit masks
      ((unsigned char*)smQ)[wv]      = (unsigned char)(bal0 & 0xffu);
      ((unsigned char*)smQ)[16 + wv] = (unsigned char)(bal1 & 0xffu);
    }
    __syncthreads();                            // postl + smQ visible

    // ---- dW + W update; thread owns column c0 ----
    unsigned long long s00 = smQ[0][0], s01 = smQ[0][1];
    unsigned long long s10 = smQ[1][0], s11 = smQ[1][1];
    int pc0 = __popcll(s00) + __popcll(s01);
    int pc1 = __popcll(s10) + __popcll(s11);
    const __hip_bfloat16* prt = pre + (size_t)t*(BB*INF);
    if (hasc) DOCOL(c0, cl0, sv0)

    lA=lAn; cn=cnn; cl0=cl0n; sv0=sv0n;
  }

  __syncthreads();
  // ---- outputs: [W (400x784)] [mem (128x400)] [syn (128x400)] [counts (400)] ----
  if (tid < INF){
    float2 wvv = Wp2[tid];
    out[(size_t)n0*INF + tid]       = wvv.x;
    out[(size_t)(n0+1)*INF + tid]   = wvv.y;
  }
  if (q == 0){
    out[(size_t)NNEU*INF + (size_t)b*NNEU + n0]                        = mem0;
    out[(size_t)NNEU*INF + (size_t)b*NNEU + n0 + 1]                    = mem1;
    out[(size_t)NNEU*INF + (size_t)BB*NNEU + (size_t)b*NNEU + n0]      = syn0;
    out[(size_t)NNEU*INF + (size_t)BB*NNEU + (size_t)b*NNEU + n0 + 1]  = syn1;
    atomicAdd(&cntS[0], sc0);
    atomicAdd(&cntS[1], sc1);
  }
  __syncthreads();
  if (tid < 2) out[(size_t)NNEU*INF + 2*(size_t)BB*NNEU + n0 + tid] = cntS[tid];
}

extern "C" void kernel_launch(void* const* d_in, const int* in_sizes, int n_in,
                              void* d_out, int out_size, void* d_ws, size_t ws_size,
                              hipStream_t stream) {
  const float* img = (const float*)d_in[0];   // [T,B,IN] float32 (0/1)
  const float* W   = (const float*)d_in[1];   // [N,IN] float32
  float* out = (float*)d_out;

  // workspace carve (total 87,472,000 B)
  char* ws = (char*)d_ws;
  __hip_bfloat16* pre  = (__hip_bfloat16*)ws;                  // 70,246,400
  float*          S    = (float*)(ws + 70246400);              //  1,097,600
  unsigned short* lst  = (unsigned short*)(ws + 71344000);     //  7,168,000
  int*            cnts = (int*)(ws + 78512000);                //    179,200
  unsigned int*   coll = (unsigned int*)(ws + 78691200);       //  8,780,800

  k_pretr  <<<(BB*INF + 255)/256, 256, 0, stream>>>(img, pre);
  k_S      <<<(TT*INF + 255)/256, 256, 0, stream>>>(pre, S);
  k_rowlist<<<(TT*BB*64)/256,     256, 0, stream>>>(img, lst, cnts);
  k_collist<<<(TT*INF + 255)/256, 256, 0, stream>>>(img, coll);
  k_main   <<<NNEU/NS, NTHR, 0, stream>>>(W, pre, S, lst, cnts, coll, out);
}